// Round 24
// baseline (41.685 us; speedup 1.0000x reference)
//
#include <hip/hip_runtime.h>

// UDTCWT fully-fused r24 = r23 (40.29us, best) + ONE change: W=15 -> 19 in
// all dilated levels (reads/output 1.60 -> 1.47; G=512-552 <= 768; live set
// ~74 VGPR <= 85 budget; no new branches -- unlike r16's spill-mess).
// lvl1 direct-from-global + tail guard (r23), interleaved quads (r20),
// staged D2/D4/D8 psi via P.
// B=4, C=8 -> 16 chains, T=65536. Output: yl [4][8][T], yh [8][4][16][T].

static constexpr int B  = 4;
static constexpr int C2 = 16;
static constexpr int T  = 65536;
static constexpr int NT = 768;
static constexpr int TS = 8192;
static constexpr int HB = 1152;
static constexpr int S  = TS + 2 * HB;   // 10496 floats = 41.98 KB

__device__ __forceinline__ float rfl(float x) {
    return __int_as_float(__builtin_amdgcn_readfirstlane(__float_as_int(x)));
}

// LDS-only barrier (measured neutral vs __syncthreads in r11).
__device__ __forceinline__ void bar_lds() {
    asm volatile("s_waitcnt lgkmcnt(0)" ::: "memory");
    __builtin_amdgcn_s_barrier();
}

// Margin chain: lvl1 out 1148; each dilated level consumes 4.5*D:
// 1136(D2) 1116(D4) 1080(D8) 1008(D16) 864(D32) 576(D64) 0(D128).

// ---------- Level 1 (D=1), DIRECT from global, interleaved quads ----------
template <int SH>
__device__ __forceinline__ void f_lvl1(
    const float* __restrict__ xin, float* __restrict__ A,
    const float* __restrict__ h0o, const float* __restrict__ h1o,
    float* __restrict__ psi_g, int gbase, int tid)
{
    float f0[5], f1[7];
#pragma unroll
    for (int k = 0; k < 5; ++k) f0[k] = rfl(h0o[k]);
#pragma unroll
    for (int k = 0; k < 7; ++k) f1[k] = rfl(h1o[k]);

    constexpr int OFF   = SH ? 1 : 2;
    constexpr int FS    = SH ? 2 : 0;
    constexpr int MO    = 1148;
    constexpr int START = HB - MO;            // 4 (%4==0)
    constexpr int NQ    = (TS + 2 * MO) / 4;  // 2622 quads
    constexpr int NR    = 4;                  // 4*768 >= 2622

#pragma unroll
    for (int r = 0; r < NR; ++r) {
        int qi = tid + r * NT;
        if (r == NR - 1 && qi >= NQ) break;   // tail guard (rounds 0-2 always ok)
        int p  = START + qi * 4;
        float w[12];
#pragma unroll
        for (int j = 0; j < 3; ++j) {
            int gg = gbase + p - 4 + 4 * j;   // %4==0: quad fully in or out
            *(float4*)&w[4 * j] = ((unsigned)gg < (unsigned)T)
                ? *(const float4*)&xin[gg]
                : make_float4(0.f, 0.f, 0.f, 0.f);
        }
        float a[4], bb[4];
#pragma unroll
        for (int i = 0; i < 4; ++i) {
            float sa = 0.f, sb = 0.f;
#pragma unroll
            for (int k = 0; k < 5; ++k) sa += w[i + k + FS + OFF] * f0[k];
#pragma unroll
            for (int k = 0; k < 7; ++k) sb += w[i + k + OFF] * f1[k];
            a[i] = sa; bb[i] = sb;
        }
        const bool inT = (unsigned)(gbase + p) < (unsigned)T;
        *(float4*)&A[p] = inT ? make_float4(a[0], a[1], a[2], a[3])
                              : make_float4(0.f, 0.f, 0.f, 0.f);
        if ((unsigned)(p - HB) < (unsigned)TS)
            *(float4*)&psi_g[gbase + p] = make_float4(bb[0], bb[1], bb[2], bb[3]);
    }
}

// ---------- Dilated level, in-place; STAGE -> psi via LDS stage buffer ----------
template <int D, int W, int MO, bool STAGE, bool LAST>
__device__ __forceinline__ void f_level(
    float* __restrict__ buf, float* __restrict__ psi_st,
    const float (&f0)[10], const float (&f1)[10],
    float* __restrict__ psi_g, float* __restrict__ yl_g,
    int gbase, int tid, bool wr_yl)
{
    constexpr int HALF  = 9 * D / 2;
    constexpr int START = HB - MO;
    constexpr int N     = TS + 2 * MO;
    static_assert(N % D == 0, "");
    constexpr int NPD   = N / D;
    static_assert(NPD >= W, "");
    constexpr int CPC   = (NPD + W - 1) / W;
    constexpr int G     = D * CPC;
    static_assert(G <= NT, "single chunk per thread required");
    constexpr int LOG2D = (D == 2 ? 1 : D == 4 ? 2 : D == 8 ? 3 :
                           D == 16 ? 4 : D == 32 ? 5 : D == 64 ? 6 : 7);

    float a[W], bb[W];
    int p0 = 0;
    const bool act = tid < G;
    const bool do_phi = !LAST || wr_yl;     // block-uniform
    if (act) {
        int r  = tid & (D - 1);
        int q  = tid >> LOG2D;
        int ms = q * W;
        if (ms > NPD - W) ms = NPD - W;     // clamp (dup work, benign)
        p0 = START + r + ms * D;

        float v[W + 9];
#pragma unroll
        for (int n = 0; n < W + 9; ++n) v[n] = buf[p0 - HALF + n * D];
#pragma unroll
        for (int m = 0; m < W; ++m) { a[m] = 0.f; bb[m] = 0.f; }
        if (do_phi) {
#pragma unroll
            for (int k = 0; k < 10; ++k)
#pragma unroll
                for (int m = 0; m < W; ++m) {
                    float x = v[m + k];
                    a[m] += x * f0[k]; bb[m] += x * f1[k];
                }
        } else {
#pragma unroll
            for (int k = 0; k < 10; ++k)
#pragma unroll
                for (int m = 0; m < W; ++m) bb[m] += v[m + k] * f1[k];
        }
    }
    bar_lds();
    if (act) {
#pragma unroll
        for (int m = 0; m < W; ++m) {
            int p = p0 + m * D;
            const bool core = (unsigned)(p - HB) < (unsigned)TS;
            if (core) {
                if constexpr (STAGE) psi_st[p - HB] = bb[m];
                else                 psi_g[gbase + p] = bb[m];
            }
            if constexpr (!LAST) {
                buf[p] = ((unsigned)(gbase + p) < (unsigned)T) ? a[m] : 0.f;
            } else {
                if (wr_yl && core) yl_g[gbase + p] = a[m];
            }
        }
    }
    bar_lds();
}

// Coalesced copy psi_st -> global (overlaps next level's compute phase).
__device__ __forceinline__ void f_copyout(
    const float* __restrict__ psi_st, float* __restrict__ dst, int tid)
{
    for (int i4 = tid * 4; i4 < TS; i4 += NT * 4)
        *(float4*)&dst[i4] = *(const float4*)&psi_st[i4];
}

__global__ __launch_bounds__(768, 6) void udtcwt_fused(
    const float* __restrict__ x,
    const float* __restrict__ h0o, const float* __restrict__ h1o,
    const float* __restrict__ h0a, const float* __restrict__ h1a,
    const float* __restrict__ h0b, const float* __restrict__ h1b,
    float* __restrict__ out)
{
    __shared__ float A[S];       // 41.98 KB, in-place phi chain
    __shared__ float P[TS];      // 32 KB psi stage (D2, D4, D8)

    const int tid   = threadIdx.x;
    const int bid   = blockIdx.x;
    const int tile  = bid & 7;           // 8 tiles of 8192
    const int chain = bid >> 3;          // 0..63
    const int shbit = chain & 1;
    const int cx    = (chain >> 1) & 7;
    const int b     = chain >> 4;
    const int c2    = shbit * 8 + cx;
    const int t0    = tile * TS;
    const int gbase = t0 - HB;           // %4 == 0

    const float* xin = x + (size_t)(b * 8 + cx) * T;

    float f0[10], f1[10];
    {
        const float* F0 = (c2 & 1) ? h0b : h0a;
        const float* F1 = (c2 & 1) ? h1b : h1a;
#pragma unroll
        for (int k = 0; k < 10; ++k) { f0[k] = rfl(F0[k]); f1[k] = rfl(F1[k]); }
    }

    float* yl_g = out + (size_t)(b * 8 + c2) * T;    // used when c2<8
    float* yh   = out + (size_t)B * 8 * T;
    const size_t LS = (size_t)B * C2 * T;
    float* psi0 = yh + (size_t)(b * C2 + c2) * T;
    const bool wr_yl = (c2 < 8);

    // lvl1 straight from global; phi lands in A inline (A dead before this)
    if (shbit) f_lvl1<1>(xin, A, h0o, h1o, psi0, gbase, tid);
    else       f_lvl1<0>(xin, A, h0o, h1o, psi0, gbase, tid);
    bar_lds();                           // A visible to all waves

    f_level<  2, 19, 1136, true,  false>(A, P, f0, f1, nullptr, nullptr, gbase, tid, false);
    f_copyout(P, psi0 + 1 * LS + t0, tid);
    f_level<  4, 19, 1116, true,  false>(A, P, f0, f1, nullptr, nullptr, gbase, tid, false);
    f_copyout(P, psi0 + 2 * LS + t0, tid);
    f_level<  8, 19, 1080, true,  false>(A, P, f0, f1, nullptr, nullptr, gbase, tid, false);
    f_copyout(P, psi0 + 3 * LS + t0, tid);
    f_level< 16, 19, 1008, false, false>(A, P, f0, f1, psi0 + 4 * LS, nullptr, gbase, tid, false);
    f_level< 32, 19,  864, false, false>(A, P, f0, f1, psi0 + 5 * LS, nullptr, gbase, tid, false);
    f_level< 64, 19,  576, false, false>(A, P, f0, f1, psi0 + 6 * LS, nullptr, gbase, tid, false);
    f_level<128, 19,    0, false, true >(A, P, f0, f1, psi0 + 7 * LS, yl_g,    gbase, tid, wr_yl);
}

extern "C" void kernel_launch(void* const* d_in, const int* in_sizes, int n_in,
                              void* d_out, int out_size, void* d_ws, size_t ws_size,
                              hipStream_t stream)
{
    const float* x   = (const float*)d_in[0];
    const float* h0o = (const float*)d_in[1];
    const float* h1o = (const float*)d_in[2];
    const float* h0a = (const float*)d_in[3];
    const float* h1a = (const float*)d_in[4];
    const float* h0b = (const float*)d_in[5];
    const float* h1b = (const float*)d_in[6];

    const int nblocks = 64 * (T / TS);   // 512
    udtcwt_fused<<<nblocks, NT, 0, stream>>>(x, h0o, h1o, h0a, h1a, h0b, h1b,
                                             (float*)d_out);
}

// Round 25
// 40.198 us; speedup vs baseline: 1.0370x; 1.0370x over previous
//
#include <hip/hip_runtime.h>

// UDTCWT fully-fused FINAL = r23 (40.29us, best measured).
// History: 161.5 (r1 baseline) -> 69.4 (fused LDS cascade) -> 57.2 (polyphase)
// -> 50.4 (split+residency) -> 43.9 (refused, in-place+b128) -> 42.7 (lvl1
// interleave, bank-conflict fix) -> 40.5 (lvl1 direct-from-global) -> 40.29
// (tail guard). W=15 verified optimal (19 spills: VGPR 40-collapse, r24;
// 13/14 raise LDS insts/output, r15). Stage/direct crossover: D<=8 staged.
// SQ_LDS_BANK_CONFLICT = 0 (r24 PMC). Remaining gap to ~25us HBM floor is
// barrier-phase serialization at 2 blocks/CU; all scheduling restructures
// (early stores r18, ping-pong r19, LDS-only barriers r11) tested <= neutral.
// B=4, C=8 -> 16 chains, T=65536. Output: yl [4][8][T], yh [8][4][16][T].

static constexpr int B  = 4;
static constexpr int C2 = 16;
static constexpr int T  = 65536;
static constexpr int NT = 768;
static constexpr int TS = 8192;
static constexpr int HB = 1152;
static constexpr int S  = TS + 2 * HB;   // 10496 floats = 41.98 KB

__device__ __forceinline__ float rfl(float x) {
    return __int_as_float(__builtin_amdgcn_readfirstlane(__float_as_int(x)));
}

// LDS-only barrier (measured neutral vs __syncthreads in r11).
__device__ __forceinline__ void bar_lds() {
    asm volatile("s_waitcnt lgkmcnt(0)" ::: "memory");
    __builtin_amdgcn_s_barrier();
}

// Margin chain: lvl1 out 1148; each dilated level consumes 4.5*D:
// 1136(D2) 1116(D4) 1080(D8) 1008(D16) 864(D32) 576(D64) 0(D128).

// ---------- Level 1 (D=1), DIRECT from global, interleaved quads ----------
template <int SH>
__device__ __forceinline__ void f_lvl1(
    const float* __restrict__ xin, float* __restrict__ A,
    const float* __restrict__ h0o, const float* __restrict__ h1o,
    float* __restrict__ psi_g, int gbase, int tid)
{
    float f0[5], f1[7];
#pragma unroll
    for (int k = 0; k < 5; ++k) f0[k] = rfl(h0o[k]);
#pragma unroll
    for (int k = 0; k < 7; ++k) f1[k] = rfl(h1o[k]);

    constexpr int OFF   = SH ? 1 : 2;
    constexpr int FS    = SH ? 2 : 0;
    constexpr int MO    = 1148;
    constexpr int START = HB - MO;            // 4 (%4==0)
    constexpr int NQ    = (TS + 2 * MO) / 4;  // 2622 quads
    constexpr int NR    = 4;                  // 4*768 >= 2622

#pragma unroll
    for (int r = 0; r < NR; ++r) {
        int qi = tid + r * NT;
        if (r == NR - 1 && qi >= NQ) break;   // tail guard (rounds 0-2 always ok)
        int p  = START + qi * 4;
        float w[12];
#pragma unroll
        for (int j = 0; j < 3; ++j) {
            int gg = gbase + p - 4 + 4 * j;   // %4==0: quad fully in or out
            *(float4*)&w[4 * j] = ((unsigned)gg < (unsigned)T)
                ? *(const float4*)&xin[gg]
                : make_float4(0.f, 0.f, 0.f, 0.f);
        }
        float a[4], bb[4];
#pragma unroll
        for (int i = 0; i < 4; ++i) {
            float sa = 0.f, sb = 0.f;
#pragma unroll
            for (int k = 0; k < 5; ++k) sa += w[i + k + FS + OFF] * f0[k];
#pragma unroll
            for (int k = 0; k < 7; ++k) sb += w[i + k + OFF] * f1[k];
            a[i] = sa; bb[i] = sb;
        }
        const bool inT = (unsigned)(gbase + p) < (unsigned)T;
        *(float4*)&A[p] = inT ? make_float4(a[0], a[1], a[2], a[3])
                              : make_float4(0.f, 0.f, 0.f, 0.f);
        if ((unsigned)(p - HB) < (unsigned)TS)
            *(float4*)&psi_g[gbase + p] = make_float4(bb[0], bb[1], bb[2], bb[3]);
    }
}

// ---------- Dilated level, in-place; STAGE -> psi via LDS stage buffer ----------
template <int D, int W, int MO, bool STAGE, bool LAST>
__device__ __forceinline__ void f_level(
    float* __restrict__ buf, float* __restrict__ psi_st,
    const float (&f0)[10], const float (&f1)[10],
    float* __restrict__ psi_g, float* __restrict__ yl_g,
    int gbase, int tid, bool wr_yl)
{
    constexpr int HALF  = 9 * D / 2;
    constexpr int START = HB - MO;
    constexpr int N     = TS + 2 * MO;
    static_assert(N % D == 0, "");
    constexpr int NPD   = N / D;
    static_assert(NPD >= W, "");
    constexpr int CPC   = (NPD + W - 1) / W;
    constexpr int G     = D * CPC;
    static_assert(G <= NT, "single chunk per thread required");
    constexpr int LOG2D = (D == 2 ? 1 : D == 4 ? 2 : D == 8 ? 3 :
                           D == 16 ? 4 : D == 32 ? 5 : D == 64 ? 6 : 7);

    float a[W], bb[W];
    int p0 = 0;
    const bool act = tid < G;
    const bool do_phi = !LAST || wr_yl;     // block-uniform
    if (act) {
        int r  = tid & (D - 1);
        int q  = tid >> LOG2D;
        int ms = q * W;
        if (ms > NPD - W) ms = NPD - W;     // clamp (dup work, benign)
        p0 = START + r + ms * D;

        float v[W + 9];
#pragma unroll
        for (int n = 0; n < W + 9; ++n) v[n] = buf[p0 - HALF + n * D];
#pragma unroll
        for (int m = 0; m < W; ++m) { a[m] = 0.f; bb[m] = 0.f; }
        if (do_phi) {
#pragma unroll
            for (int k = 0; k < 10; ++k)
#pragma unroll
                for (int m = 0; m < W; ++m) {
                    float x = v[m + k];
                    a[m] += x * f0[k]; bb[m] += x * f1[k];
                }
        } else {
#pragma unroll
            for (int k = 0; k < 10; ++k)
#pragma unroll
                for (int m = 0; m < W; ++m) bb[m] += v[m + k] * f1[k];
        }
    }
    bar_lds();
    if (act) {
#pragma unroll
        for (int m = 0; m < W; ++m) {
            int p = p0 + m * D;
            const bool core = (unsigned)(p - HB) < (unsigned)TS;
            if (core) {
                if constexpr (STAGE) psi_st[p - HB] = bb[m];
                else                 psi_g[gbase + p] = bb[m];
            }
            if constexpr (!LAST) {
                buf[p] = ((unsigned)(gbase + p) < (unsigned)T) ? a[m] : 0.f;
            } else {
                if (wr_yl && core) yl_g[gbase + p] = a[m];
            }
        }
    }
    bar_lds();
}

// Coalesced copy psi_st -> global (overlaps next level's compute phase).
__device__ __forceinline__ void f_copyout(
    const float* __restrict__ psi_st, float* __restrict__ dst, int tid)
{
    for (int i4 = tid * 4; i4 < TS; i4 += NT * 4)
        *(float4*)&dst[i4] = *(const float4*)&psi_st[i4];
}

__global__ __launch_bounds__(768, 6) void udtcwt_fused(
    const float* __restrict__ x,
    const float* __restrict__ h0o, const float* __restrict__ h1o,
    const float* __restrict__ h0a, const float* __restrict__ h1a,
    const float* __restrict__ h0b, const float* __restrict__ h1b,
    float* __restrict__ out)
{
    __shared__ float A[S];       // 41.98 KB, in-place phi chain
    __shared__ float P[TS];      // 32 KB psi stage (D2, D4, D8)

    const int tid   = threadIdx.x;
    const int bid   = blockIdx.x;
    const int tile  = bid & 7;           // 8 tiles of 8192
    const int chain = bid >> 3;          // 0..63
    const int shbit = chain & 1;
    const int cx    = (chain >> 1) & 7;
    const int b     = chain >> 4;
    const int c2    = shbit * 8 + cx;
    const int t0    = tile * TS;
    const int gbase = t0 - HB;           // %4 == 0

    const float* xin = x + (size_t)(b * 8 + cx) * T;

    float f0[10], f1[10];
    {
        const float* F0 = (c2 & 1) ? h0b : h0a;
        const float* F1 = (c2 & 1) ? h1b : h1a;
#pragma unroll
        for (int k = 0; k < 10; ++k) { f0[k] = rfl(F0[k]); f1[k] = rfl(F1[k]); }
    }

    float* yl_g = out + (size_t)(b * 8 + c2) * T;    // used when c2<8
    float* yh   = out + (size_t)B * 8 * T;
    const size_t LS = (size_t)B * C2 * T;
    float* psi0 = yh + (size_t)(b * C2 + c2) * T;
    const bool wr_yl = (c2 < 8);

    // lvl1 straight from global; phi lands in A inline (A dead before this)
    if (shbit) f_lvl1<1>(xin, A, h0o, h1o, psi0, gbase, tid);
    else       f_lvl1<0>(xin, A, h0o, h1o, psi0, gbase, tid);
    bar_lds();                           // A visible to all waves

    f_level<  2, 15, 1136, true,  false>(A, P, f0, f1, nullptr, nullptr, gbase, tid, false);
    f_copyout(P, psi0 + 1 * LS + t0, tid);
    f_level<  4, 15, 1116, true,  false>(A, P, f0, f1, nullptr, nullptr, gbase, tid, false);
    f_copyout(P, psi0 + 2 * LS + t0, tid);
    f_level<  8, 15, 1080, true,  false>(A, P, f0, f1, nullptr, nullptr, gbase, tid, false);
    f_copyout(P, psi0 + 3 * LS + t0, tid);
    f_level< 16, 15, 1008, false, false>(A, P, f0, f1, psi0 + 4 * LS, nullptr, gbase, tid, false);
    f_level< 32, 15,  864, false, false>(A, P, f0, f1, psi0 + 5 * LS, nullptr, gbase, tid, false);
    f_level< 64, 15,  576, false, false>(A, P, f0, f1, psi0 + 6 * LS, nullptr, gbase, tid, false);
    f_level<128, 15,    0, false, true >(A, P, f0, f1, psi0 + 7 * LS, yl_g,    gbase, tid, wr_yl);
}

extern "C" void kernel_launch(void* const* d_in, const int* in_sizes, int n_in,
                              void* d_out, int out_size, void* d_ws, size_t ws_size,
                              hipStream_t stream)
{
    const float* x   = (const float*)d_in[0];
    const float* h0o = (const float*)d_in[1];
    const float* h1o = (const float*)d_in[2];
    const float* h0a = (const float*)d_in[3];
    const float* h1a = (const float*)d_in[4];
    const float* h0b = (const float*)d_in[5];
    const float* h1b = (const float*)d_in[6];

    const int nblocks = 64 * (T / TS);   // 512
    udtcwt_fused<<<nblocks, NT, 0, stream>>>(x, h0o, h1o, h0a, h1a, h0b, h1b,
                                             (float*)d_out);
}